// Round 1
// baseline (274.622 us; speedup 1.0000x reference)
//
#include <hip/hip_runtime.h>
#include <math.h>

// Problem constants
#define B_  8
#define C_  64
#define O_  64
#define H_  128
#define W_  128
#define K_  9
#define OFFC_ 18   // 2*K
#define HW_ (H_*W_)

// ws layout (floats):
//   xt   : [B][H][W][C]        8*128*128*64 = 8388608
//   offs : [B][H][W][18]       8*128*128*18 = 2359296
//   wt   : [9][C][O]           9*64*64      = 36864
#define XT_ELEMS   (8388608)
#define OFFS_ELEMS (2359296)
#define WT_ELEMS   (36864)

// ---------------------------------------------------------------------------
// Kernel 1: NCHW -> NHWC transpose of x
// grid: B*H*(W/64) = 2048 blocks, 256 threads
// ---------------------------------------------------------------------------
__global__ __launch_bounds__(256) void k_transpose(const float* __restrict__ x,
                                                   float* __restrict__ xt) {
    __shared__ float tile[64][65];
    int gid = blockIdx.x;
    int w0 = (gid & 1) * 64;
    int h  = (gid >> 1) & 127;
    int b  = gid >> 8;
    int tid = threadIdx.x;

    int lw = tid & 63;      // 0..63 within row
    int cq = tid >> 6;      // 0..3
    const float* xb = x + ((size_t)b * C_) * HW_ + (size_t)h * W_;
    #pragma unroll
    for (int it = 0; it < 16; ++it) {
        int c = it * 4 + cq;
        tile[c][lw] = xb[(size_t)c * HW_ + w0 + lw];
    }
    __syncthreads();
    float* xo = xt + (((size_t)b * H_ + h) * W_ + w0) * C_;
    int lc = tid & 63;
    int pq = tid >> 6;
    #pragma unroll
    for (int it = 0; it < 16; ++it) {
        int p = it * 4 + pq;
        xo[(size_t)p * C_ + lc] = tile[lc][p];
    }
}

// ---------------------------------------------------------------------------
// Kernel 2: weight (O,C,3,3) -> wt[k][c][o]
// ---------------------------------------------------------------------------
__global__ void k_wtrans(const float* __restrict__ w, float* __restrict__ wt) {
    int i = blockIdx.x * 256 + threadIdx.x;
    if (i < K_ * C_ * O_) {
        int o = i & 63;
        int c = (i >> 6) & 63;
        int k = i >> 12;
        wt[i] = w[(o * C_ + c) * K_ + k];
    }
}

// ---------------------------------------------------------------------------
// Kernel 3: offset conv (3x3, C=64 -> 18) + bias + clip to +-8
// one thread per output pixel; weights staged in LDS as wl[kk][o][c]
// grid: 131072/256 = 512 blocks
// ---------------------------------------------------------------------------
__global__ __launch_bounds__(256) void k_offconv(const float* __restrict__ xt,
                                                 const float* __restrict__ off_w,
                                                 const float* __restrict__ off_b,
                                                 float* __restrict__ offs) {
    __shared__ float wl[K_][OFFC_][C_];   // 41.5 KB
    __shared__ float bl[OFFC_];
    int tid = threadIdx.x;
    for (int i = tid; i < K_ * OFFC_ * C_; i += 256) {
        int c  = i & 63;
        int o  = (i >> 6) % OFFC_;
        int kk = i / (OFFC_ * C_);
        wl[kk][o][c] = off_w[(o * C_ + c) * K_ + kk];
    }
    if (tid < OFFC_) bl[tid] = off_b[tid];
    __syncthreads();

    int pid = blockIdx.x * 256 + tid;
    int w = pid & 127;
    int h = (pid >> 7) & 127;
    int b = pid >> 14;

    float acc[OFFC_];
    #pragma unroll
    for (int o = 0; o < OFFC_; ++o) acc[o] = bl[o];

    #pragma unroll 1
    for (int ky = 0; ky < 3; ++ky) {
        int y = h + ky - 1;
        if (y < 0 || y >= H_) continue;
        #pragma unroll 1
        for (int kx = 0; kx < 3; ++kx) {
            int x = w + kx - 1;
            if (x < 0 || x >= W_) continue;
            int kk = ky * 3 + kx;
            const float4* src = (const float4*)(xt + (((size_t)b * H_ + y) * W_ + x) * C_);
            float4 xv[16];
            #pragma unroll
            for (int q = 0; q < 16; ++q) xv[q] = src[q];
            #pragma unroll 1
            for (int o = 0; o < OFFC_; ++o) {
                const float4* wr = (const float4*)wl[kk][o];
                float s = 0.f;
                #pragma unroll
                for (int q = 0; q < 16; ++q) {
                    float4 wv = wr[q];
                    s += xv[q].x * wv.x + xv[q].y * wv.y + xv[q].z * wv.z + xv[q].w * wv.w;
                }
                acc[o] += s;
            }
        }
    }
    float* op = offs + (size_t)pid * OFFC_;
    #pragma unroll
    for (int o = 0; o < OFFC_; ++o) {
        float v = acc[o];
        v = fminf(8.0f, fmaxf(-8.0f, v));
        op[o] = v;
    }
}

// ---------------------------------------------------------------------------
// Kernel 4: deformable conv main.
// Block: 256 threads, tile = 64 pixels (one b, one h, w0..w0+63) x 64 outputs.
// Per k (9): stage wt[k] slice [c][o] in LDS, bilinear-sample samp[c][p] in LDS,
// then 4x4-microtile FMA GEMM accumulating out[p][o].
// grid: 2048 blocks
// ---------------------------------------------------------------------------
__global__ __launch_bounds__(256) void k_deform(const float* __restrict__ xt,
                                                const float* __restrict__ offs,
                                                const float* __restrict__ wt,
                                                float* __restrict__ out) {
    __shared__ float offl[64][OFFC_];   // 4.6 KB
    __shared__ float samp[C_][64];      // [c][p] 16 KB
    __shared__ float wtile[C_][O_];     // [c][o] 16 KB

    int gid = blockIdx.x;
    int w0 = (gid & 1) * 64;
    int h  = (gid >> 1) & 127;
    int b  = gid >> 8;
    int tid = threadIdx.x;

    // load offsets for the 64 pixels
    {
        float* ofl = &offl[0][0];
        const float* osrc = offs + (((size_t)b * H_ + h) * W_ + w0) * OFFC_;
        for (int i = tid; i < 64 * OFFC_; i += 256) ofl[i] = osrc[i];
    }

    // accumulators: 4 pixels (vector) x 4 outputs
    float4 a0 = make_float4(0, 0, 0, 0), a1 = a0, a2 = a0, a3 = a0;

    int p  = tid >> 2;          // sampling: pixel 0..63
    int cg = tid & 3;           // channel group 0..3 (16 ch each)
    int c0 = cg * 16;
    int pp = (tid & 15) << 2;   // gemm: pixel base
    int oo = (tid >> 4) << 2;   // gemm: output base

    #pragma unroll 1
    for (int k = 0; k < K_; ++k) {
        __syncthreads();   // previous GEMM reads done (also covers offl @ k=0)

        // stage weight slice wt[k][c][o] -> wtile
        {
            const float4* wsrc = (const float4*)(wt + (size_t)k * C_ * O_);
            float4* wdst = (float4*)&wtile[0][0];
            #pragma unroll
            for (int q = 0; q < 4; ++q) wdst[q * 256 + tid] = wsrc[q * 256 + tid];
        }

        // bilinear sampling: this thread does pixel p, channels c0..c0+15
        {
            float oy = offl[p][2 * k];
            float ox = offl[p][2 * k + 1];
            float sy = oy + (float)(k / 3) + (float)(h - 1);
            float sx = ox + (float)(k % 3) + (float)(w0 + p - 1);
            float y0f = floorf(sy);
            float x0f = floorf(sx);
            float ty = sy - y0f;
            float tx = sx - x0f;
            int y0 = (int)y0f;
            int x0 = (int)x0f;

            float4 sr[4];
            #pragma unroll
            for (int q = 0; q < 4; ++q) sr[q] = make_float4(0, 0, 0, 0);

            #pragma unroll
            for (int dy = 0; dy < 2; ++dy) {
                int yc = y0 + dy;
                if (yc < 0 || yc >= H_) continue;
                float wy = dy ? ty : 1.0f - ty;
                #pragma unroll
                for (int dx = 0; dx < 2; ++dx) {
                    int xc = x0 + dx;
                    if (xc < 0 || xc >= W_) continue;
                    float wgt = wy * (dx ? tx : 1.0f - tx);
                    const float4* src = (const float4*)(xt + (((size_t)b * H_ + yc) * W_ + xc) * C_ + c0);
                    #pragma unroll
                    for (int q = 0; q < 4; ++q) {
                        float4 v = src[q];
                        sr[q].x += wgt * v.x;
                        sr[q].y += wgt * v.y;
                        sr[q].z += wgt * v.z;
                        sr[q].w += wgt * v.w;
                    }
                }
            }
            #pragma unroll
            for (int q = 0; q < 4; ++q) {
                samp[c0 + q * 4 + 0][p] = sr[q].x;
                samp[c0 + q * 4 + 1][p] = sr[q].y;
                samp[c0 + q * 4 + 2][p] = sr[q].z;
                samp[c0 + q * 4 + 3][p] = sr[q].w;
            }
        }
        __syncthreads();

        // GEMM: acc[p][o] += samp[c][p] * wtile[c][o]
        #pragma unroll 4
        for (int c = 0; c < C_; ++c) {
            float4 sv = *(const float4*)&samp[c][pp];
            float4 wv = *(const float4*)&wtile[c][oo];
            a0.x += sv.x * wv.x; a0.y += sv.y * wv.x; a0.z += sv.z * wv.x; a0.w += sv.w * wv.x;
            a1.x += sv.x * wv.y; a1.y += sv.y * wv.y; a1.z += sv.z * wv.y; a1.w += sv.w * wv.y;
            a2.x += sv.x * wv.z; a2.y += sv.y * wv.z; a2.z += sv.z * wv.z; a2.w += sv.w * wv.z;
            a3.x += sv.x * wv.w; a3.y += sv.y * wv.w; a3.z += sv.z * wv.w; a3.w += sv.w * wv.w;
        }
    }

    // epilogue: out[b][o][h][w]
    size_t ob = (((size_t)b * O_ + oo) * H_ + h) * W_ + w0 + pp;
    *(float4*)(out + ob)             = a0;
    *(float4*)(out + ob + HW_)       = a1;
    *(float4*)(out + ob + 2 * HW_)   = a2;
    *(float4*)(out + ob + 3 * HW_)   = a3;
}

// ---------------------------------------------------------------------------
extern "C" void kernel_launch(void* const* d_in, const int* in_sizes, int n_in,
                              void* d_out, int out_size, void* d_ws, size_t ws_size,
                              hipStream_t stream) {
    const float* x      = (const float*)d_in[0];
    const float* weight = (const float*)d_in[1];
    const float* off_w  = (const float*)d_in[2];
    const float* off_b  = (const float*)d_in[3];
    float* out = (float*)d_out;

    float* xt   = (float*)d_ws;
    float* offs = xt + XT_ELEMS;
    float* wt   = offs + OFFS_ELEMS;

    k_transpose<<<2048, 256, 0, stream>>>(x, xt);
    k_wtrans<<<(K_ * C_ * O_ + 255) / 256, 256, 0, stream>>>(weight, wt);
    k_offconv<<<512, 256, 0, stream>>>(xt, off_w, off_b, offs);
    k_deform<<<2048, 256, 0, stream>>>(xt, offs, wt, out);
}

// Round 2
// 91.879 us; speedup vs baseline: 2.9890x; 2.9890x over previous
//
#include <hip/hip_runtime.h>
#include <math.h>

typedef float  f32x4  __attribute__((ext_vector_type(4)));
typedef __bf16 bf16x8 __attribute__((ext_vector_type(8)));

#define B_  8
#define C_  64
#define O_  64
#define H_  128
#define W_  128
#define K_  9
#define OFFC_ 18
#define HW_ (H_*W_)

// LDS row swizzle for 128-byte rows read as ds_read_b128 (T2 / G4)
#define SWZ(row, cb) ((row)*128 + ((cb) ^ (((row)&7)<<4)))

// ws layout (bytes):
//   xtb  : [B][H][W][C] bf16   = 16777216 B
//   offs : [B][H][W][18] f32   =  9437184 B
//   wtb  : [9][64 o][64 c] bf16 =   73728 B
//   owt  : [9][32 o][64 c] bf16 =   36864 B
#define XTB_BYTES  16777216
#define OFFS_BYTES 9437184
#define WTB_BYTES  73728

// ---------------------------------------------------------------------------
// Kernel 1: NCHW f32 -> NHWC bf16
// ---------------------------------------------------------------------------
__global__ __launch_bounds__(256) void k_transpose(const float* __restrict__ x,
                                                   __bf16* __restrict__ xtb) {
    __shared__ float tile[64][65];
    int gid = blockIdx.x;
    int w0 = (gid & 1) * 64;
    int h  = (gid >> 1) & 127;
    int b  = gid >> 8;
    int tid = threadIdx.x;

    int lw = tid & 63, cq = tid >> 6;
    const float* xb = x + ((size_t)b * C_) * HW_ + (size_t)h * W_;
    #pragma unroll
    for (int it = 0; it < 16; ++it) {
        int c = it * 4 + cq;
        tile[c][lw] = xb[(size_t)c * HW_ + w0 + lw];
    }
    __syncthreads();
    int p = tid >> 2, q = tid & 3;
    bf16x8 v0, v1;
    #pragma unroll
    for (int j = 0; j < 8; ++j) {
        v0[j] = (__bf16)tile[q * 16 + j][p];
        v1[j] = (__bf16)tile[q * 16 + 8 + j][p];
    }
    __bf16* dst = xtb + (((size_t)b * H_ + h) * W_ + w0 + p) * C_ + q * 16;
    *(bf16x8*)dst = v0;
    *(bf16x8*)(dst + 8) = v1;
}

// ---------------------------------------------------------------------------
// Kernel 2: weights -> bf16, k-major rows
//   wtb[k][o][c] = weight[o][c][k]        (9*64*64)
//   owt[k][o][c] = off_w[o][c][k], o<18 else 0   (9*32*64, zero-padded)
// ---------------------------------------------------------------------------
__global__ __launch_bounds__(256) void k_wtrans(const float* __restrict__ w,
                                                const float* __restrict__ ow,
                                                __bf16* __restrict__ wtb,
                                                __bf16* __restrict__ owt) {
    int i = blockIdx.x * 256 + threadIdx.x;
    if (i < 9 * 64 * 64) {
        int c = i & 63, o = (i >> 6) & 63, k = i >> 12;
        wtb[i] = (__bf16)w[(o * 64 + c) * 9 + k];
    }
    if (i < 9 * 32 * 64) {
        int c = i & 63, o = (i >> 6) & 31, k = i >> 11;
        owt[i] = (o < OFFC_) ? (__bf16)ow[(o * 64 + c) * 9 + k] : (__bf16)0.f;
    }
}

// ---------------------------------------------------------------------------
// Kernel 3: offset conv via MFMA. Block = 64 px, 4 waves (one 16-px n-tile
// each), M = 32 (18 outputs zero-padded), K = 9 taps x 64 c.
// A (weights) staged swizzled in LDS; B fragments read directly from global.
// ---------------------------------------------------------------------------
__global__ __launch_bounds__(256) void k_offconv(const __bf16* __restrict__ xtb,
                                                 const __bf16* __restrict__ owt,
                                                 const float* __restrict__ off_b,
                                                 float* __restrict__ offs) {
    __shared__ alignas(16) short wlo[9 * 32 * 64];   // 36864 B, swizzled rows
    char* wb = (char*)wlo;
    int gid = blockIdx.x, tid = threadIdx.x;
    int w0 = (gid & 1) * 64, h = (gid >> 1) & 127, b = gid >> 8;

    const bf16x8* wsrc = (const bf16x8*)owt;
    for (int q = tid; q < 9 * 32 * 8; q += 256) {
        int tap = q >> 8, o = (q >> 3) & 31, cb = (q & 7) * 16;
        *(bf16x8*)(wb + tap * 4096 + SWZ(o, cb)) = wsrc[q];
    }

    int lane = tid & 63, wv = tid >> 6;
    int l15 = lane & 15, lg = lane >> 4;

    f32x4 acc[2];
    #pragma unroll
    for (int mi = 0; mi < 2; ++mi)
        #pragma unroll
        for (int r = 0; r < 4; ++r) {
            int o = mi * 16 + lg * 4 + r;
            acc[mi][r] = (o < OFFC_) ? off_b[o] : 0.f;
        }
    __syncthreads();

    int px = wv * 16 + l15;
    #pragma unroll
    for (int tap = 0; tap < 9; ++tap) {
        int y  = h + tap / 3 - 1;
        int xw = w0 + px + tap % 3 - 1;
        bool valid = ((unsigned)y < 128u) && ((unsigned)xw < 128u);
        const __bf16* bsrc = xtb + (((size_t)b * H_ + y) * W_ + xw) * C_ + lg * 8;
        #pragma unroll
        for (int ks = 0; ks < 2; ++ks) {
            int cb = ks * 64 + lg * 16;
            bf16x8 a0 = *(const bf16x8*)(wb + tap * 4096 + SWZ(l15, cb));
            bf16x8 a1 = *(const bf16x8*)(wb + tap * 4096 + SWZ(16 + l15, cb));
            bf16x8 bv;
            #pragma unroll
            for (int j = 0; j < 8; ++j) bv[j] = (__bf16)0.f;
            if (valid) bv = *(const bf16x8*)(bsrc + ks * 32);
            acc[0] = __builtin_amdgcn_mfma_f32_16x16x32_bf16(a0, bv, acc[0], 0, 0, 0);
            acc[1] = __builtin_amdgcn_mfma_f32_16x16x32_bf16(a1, bv, acc[1], 0, 0, 0);
        }
    }

    float* obase = offs + (((size_t)b * H_ + h) * W_ + w0 + px) * OFFC_;
    #pragma unroll
    for (int mi = 0; mi < 2; ++mi)
        #pragma unroll
        for (int r = 0; r < 4; ++r) {
            int o = mi * 16 + lg * 4 + r;
            if (o < OFFC_) obase[o] = fminf(8.f, fmaxf(-8.f, acc[mi][r]));
        }
}

// ---------------------------------------------------------------------------
// Kernel 4: deformable conv via MFMA.
// Block: 64 px x 64 o. Per tap k: stage wtb[k] (swizzled [o][c]) + bilinear
// sample samp[px][c] (fp32 interp on bf16 x, bf16 store, swizzled), then
// 4 waves x (2 m-tiles x 2 n-tiles x 2 k-steps) of 16x16x32 MFMA.
// A = weights (M=o), B = samples (N=px)  ->  D col = px  (coalesced stores).
// ---------------------------------------------------------------------------
__global__ __launch_bounds__(256) void k_deform(const __bf16* __restrict__ xtb,
                                                const float* __restrict__ offs,
                                                const __bf16* __restrict__ wtb,
                                                float* __restrict__ out) {
    __shared__ alignas(16) short wl[64 * 64];   // 8 KB  weights [o][c] swz
    __shared__ alignas(16) short sm[64 * 64];   // 8 KB  samples [px][c] swz
    __shared__ float offl[64][18];              // 4.5 KB
    char* wlb = (char*)wl;
    char* spb = (char*)sm;

    int gid = blockIdx.x, tid = threadIdx.x;
    int w0 = (gid & 1) * 64, h = (gid >> 1) & 127, b = gid >> 8;

    const float* osrc = offs + (((size_t)b * H_ + h) * W_ + w0) * OFFC_;
    for (int i = tid; i < 64 * OFFC_; i += 256) ((float*)offl)[i] = osrc[i];

    int p = tid >> 2, cq = tid & 3;
    int lane = tid & 63, wv = tid >> 6;
    int l15 = lane & 15, lg = lane >> 4;
    int m2 = (wv >> 1) * 2, n2 = (wv & 1) * 2;

    f32x4 acc[2][2];
    #pragma unroll
    for (int mi = 0; mi < 2; ++mi)
        #pragma unroll
        for (int ni = 0; ni < 2; ++ni)
            #pragma unroll
            for (int r = 0; r < 4; ++r) acc[mi][ni][r] = 0.f;

    const __bf16* xb = xtb + (size_t)b * HW_ * C_;
    float fh = (float)(h - 1);
    float fw = (float)(w0 + p - 1);

    #pragma unroll 1
    for (int k = 0; k < 9; ++k) {
        __syncthreads();
        // stage weight slice [64][64] bf16, swizzled
        const bf16x8* wsrc = (const bf16x8*)(wtb + (size_t)k * 4096);
        #pragma unroll
        for (int t = 0; t < 2; ++t) {
            int qq = tid + t * 256;
            int o = qq >> 3, cb = (qq & 7) * 16;
            *(bf16x8*)(wlb + SWZ(o, cb)) = wsrc[qq];
        }
        // bilinear sample: this thread: pixel p, channels cq*16..cq*16+15
        {
            float2 o2 = *(const float2*)&offl[p][2 * k];
            float sy = o2.x + (float)(k / 3) + fh;
            float sx = o2.y + (float)(k % 3) + fw;
            float y0f = floorf(sy), x0f = floorf(sx);
            float ty = sy - y0f, tx = sx - x0f;
            int y0 = (int)y0f, x0 = (int)x0f;
            float r[16];
            #pragma unroll
            for (int j = 0; j < 16; ++j) r[j] = 0.f;
            #pragma unroll
            for (int dy = 0; dy < 2; ++dy) {
                int yc = y0 + dy;
                if ((unsigned)yc < 128u) {
                    float wy = dy ? ty : 1.f - ty;
                    #pragma unroll
                    for (int dx = 0; dx < 2; ++dx) {
                        int xc = x0 + dx;
                        if ((unsigned)xc < 128u) {
                            float wgt = wy * (dx ? tx : 1.f - tx);
                            const bf16x8* src = (const bf16x8*)(xb + ((size_t)yc * W_ + xc) * C_ + cq * 16);
                            bf16x8 v0 = src[0], v1 = src[1];
                            #pragma unroll
                            for (int j = 0; j < 8; ++j) {
                                r[j]     += wgt * (float)v0[j];
                                r[8 + j] += wgt * (float)v1[j];
                            }
                        }
                    }
                }
            }
            bf16x8 h0, h1;
            #pragma unroll
            for (int j = 0; j < 8; ++j) { h0[j] = (__bf16)r[j]; h1[j] = (__bf16)r[8 + j]; }
            int cb0 = cq * 32;
            *(bf16x8*)(spb + SWZ(p, cb0))      = h0;
            *(bf16x8*)(spb + SWZ(p, cb0 + 16)) = h1;
        }
        __syncthreads();
        // MFMA: acc[mi][ni] over 2 k-steps
        #pragma unroll
        for (int ks = 0; ks < 2; ++ks) {
            int cb = ks * 64 + lg * 16;
            bf16x8 afr[2], bfr[2];
            #pragma unroll
            for (int mi = 0; mi < 2; ++mi) {
                int o = (m2 + mi) * 16 + l15;
                afr[mi] = *(const bf16x8*)(wlb + SWZ(o, cb));
            }
            #pragma unroll
            for (int ni = 0; ni < 2; ++ni) {
                int px = (n2 + ni) * 16 + l15;
                bfr[ni] = *(const bf16x8*)(spb + SWZ(px, cb));
            }
            #pragma unroll
            for (int mi = 0; mi < 2; ++mi)
                #pragma unroll
                for (int ni = 0; ni < 2; ++ni)
                    acc[mi][ni] = __builtin_amdgcn_mfma_f32_16x16x32_bf16(afr[mi], bfr[ni], acc[mi][ni], 0, 0, 0);
        }
    }

    // epilogue: out[b][o][h][w], D: col(lane&15)=px, row=(lane>>4)*4+r = o
    #pragma unroll
    for (int mi = 0; mi < 2; ++mi)
        #pragma unroll
        for (int ni = 0; ni < 2; ++ni)
            #pragma unroll
            for (int rr = 0; rr < 4; ++rr) {
                int o  = (m2 + mi) * 16 + lg * 4 + rr;
                int px = (n2 + ni) * 16 + l15;
                out[((size_t)b * O_ + o) * HW_ + h * W_ + w0 + px] = acc[mi][ni][rr];
            }
}

// ---------------------------------------------------------------------------
extern "C" void kernel_launch(void* const* d_in, const int* in_sizes, int n_in,
                              void* d_out, int out_size, void* d_ws, size_t ws_size,
                              hipStream_t stream) {
    const float* x      = (const float*)d_in[0];
    const float* weight = (const float*)d_in[1];
    const float* off_w  = (const float*)d_in[2];
    const float* off_b  = (const float*)d_in[3];
    float* out = (float*)d_out;

    char* ws = (char*)d_ws;
    __bf16* xtb = (__bf16*)ws;
    float*  offs = (float*)(ws + XTB_BYTES);
    __bf16* wtb = (__bf16*)(ws + XTB_BYTES + OFFS_BYTES);
    __bf16* owt = (__bf16*)(ws + XTB_BYTES + OFFS_BYTES + WTB_BYTES);

    k_transpose<<<2048, 256, 0, stream>>>(x, xtb);
    k_wtrans<<<144, 256, 0, stream>>>(weight, off_w, wtb, owt);
    k_offconv<<<2048, 256, 0, stream>>>(xtb, owt, off_b, offs);
    k_deform<<<2048, 256, 0, stream>>>(xtb, offs, wtb, out);
}

// Round 3
// 78.404 us; speedup vs baseline: 3.5027x; 1.1719x over previous
//
#include <hip/hip_runtime.h>
#include <math.h>

typedef float  f32x4  __attribute__((ext_vector_type(4)));
typedef __bf16 bf16x8 __attribute__((ext_vector_type(8)));

#define HP_     160
#define PITCH_  (HP_*64)           // 10240 elems per padded row
#define BPITCH_ (HP_*HP_*64)       // 1638400 elems per batch

// swizzled LDS row: 128B rows, XOR byte-bit 4..6 with row&7 (T2/G4)
#define SWZ(row, cb) ((row)*128 + ((cb) ^ (((row)&7)<<4)))

// ws layout (bytes):
//   xp   : [8][160][160][64] bf16 = 26214400  (zero halo of 16 px)
//   offs : [8][128][128][18] f32  =  9437184
//   wtb  : [9][64][64] bf16 pre-swizzled =  73728
//   owt  : [9][32][64] bf16 pre-swizzled =  36864
#define XP_BYTES   26214400
#define OFFS_BYTES 9437184
#define WTB_BYTES  73728

__device__ __forceinline__ void gl_lds16(const void* g, void* l) {
    __builtin_amdgcn_global_load_lds(
        (const __attribute__((address_space(1))) void*)g,
        (__attribute__((address_space(3))) void*)l, 16, 0, 0);
}

// ---------------------------------------------------------------------------
// k_prep: [0,2048) NCHW f32 -> padded NHWC bf16 ; [2048,4352) halo zero ;
//         [4352,4496) weight transpose+cast, PRE-SWIZZLED for linear gl_lds
// ---------------------------------------------------------------------------
__global__ __launch_bounds__(256) void k_prep(const float* __restrict__ x,
                                              const float* __restrict__ w,
                                              const float* __restrict__ ow,
                                              __bf16* __restrict__ xp,
                                              __bf16* __restrict__ wtb,
                                              __bf16* __restrict__ owt) {
    int gid = blockIdx.x, tid = threadIdx.x;
    if (gid < 2048) {
        __shared__ float tile[64][65];
        int w0 = (gid & 1) * 64, h = (gid >> 1) & 127, b = gid >> 8;
        int lw = tid & 63, cq4 = tid >> 6;
        const float* xb = x + ((size_t)b * 64) * 16384 + (size_t)h * 128;
        #pragma unroll
        for (int it = 0; it < 16; ++it) {
            int c = it * 4 + cq4;
            tile[c][lw] = xb[(size_t)c * 16384 + w0 + lw];
        }
        __syncthreads();
        int p = tid >> 2, q = tid & 3;
        bf16x8 v0, v1;
        #pragma unroll
        for (int j = 0; j < 8; ++j) {
            v0[j] = (__bf16)tile[q * 16 + j][p];
            v1[j] = (__bf16)tile[q * 16 + 8 + j][p];
        }
        __bf16* dst = xp + (size_t)b * BPITCH_ + (size_t)(h + 16) * PITCH_
                         + (size_t)(w0 + p + 16) * 64 + q * 16;
        *(bf16x8*)dst = v0;
        *(bf16x8*)(dst + 8) = v1;
    } else if (gid < 4352) {
        int i = (gid - 2048) * 256 + tid;
        int b, y, xc, cc;
        if (i < 327680) {             // 32 full rows (top16+bottom16) x 160 px
            b = i / 40960; int r = i % 40960;
            int row = r / 1280; y = row < 16 ? row : row + 128;
            int xi = r % 1280; xc = xi >> 3; cc = (xi & 7) * 8;
        } else {                      // side cols: rows [16,144) x 32 px
            int j = i - 327680;
            b = j / 32768; int r = j % 32768;
            y = 16 + (r >> 8);
            int xi = r & 255; int xcol = xi >> 3;
            xc = xcol < 16 ? xcol : xcol + 128; cc = (xi & 7) * 8;
        }
        bf16x8 z;
        #pragma unroll
        for (int j = 0; j < 8; ++j) z[j] = (__bf16)0.f;
        *(bf16x8*)(xp + (size_t)b * BPITCH_ + (size_t)y * PITCH_ + (size_t)xc * 64 + cc) = z;
    } else {
        int i = (gid - 4352) * 256 + tid;
        if (i < 36864) {   // wtb[k][o][c^((o&7)<<3)] = w[o][c][k]
            int c = i & 63, o = (i >> 6) & 63, k = i >> 12;
            wtb[(k << 12) + (o << 6) + (c ^ ((o & 7) << 3))] = (__bf16)w[(o * 64 + c) * 9 + k];
        }
        if (i < 18432) {   // owt[k][o][c^] = off_w[o][c][k], o>=18 -> 0
            int c = i & 63, o = (i >> 6) & 31, k = i >> 11;
            owt[(k << 11) + (o << 6) + (c ^ ((o & 7) << 3))] =
                (o < 18) ? (__bf16)ow[(o * 64 + c) * 9 + k] : (__bf16)0.f;
        }
    }
}

// ---------------------------------------------------------------------------
// k_offconv: offset conv via MFMA on padded input (branchless), owt staged
// once via linear global_load_lds (source pre-swizzled), + bias + clip.
// ---------------------------------------------------------------------------
__global__ __launch_bounds__(256) void k_offconv(const __bf16* __restrict__ xp,
                                                 const __bf16* __restrict__ owt,
                                                 const float* __restrict__ off_b,
                                                 float* __restrict__ offs) {
    __shared__ alignas(16) short wlo[9 * 32 * 64];   // 36864 B
    int gid = blockIdx.x, tid = threadIdx.x;
    int w0 = (gid & 1) * 64, h = (gid >> 1) & 127, b = gid >> 8;
    int lane = tid & 63, wv = tid >> 6, l15 = lane & 15, lg = lane >> 4;

    {
        const char* s = (const char*)owt + wv * 9216 + lane * 16;
        char* d = (char*)wlo + wv * 9216;
        #pragma unroll
        for (int it = 0; it < 9; ++it) gl_lds16(s + it * 1024, d + it * 1024);
    }

    f32x4 acc0, acc1;
    #pragma unroll
    for (int r = 0; r < 4; ++r) {
        int o = lg * 4 + r;
        acc0[r] = (o < 18) ? off_b[o] : 0.f;
        acc1[r] = (o + 16 < 18) ? off_b[o + 16] : 0.f;
    }
    __syncthreads();

    int px = wv * 16 + l15;
    const __bf16* pbase = xp + (size_t)b * BPITCH_ + (size_t)(h + 15) * PITCH_
                             + (size_t)(w0 + px + 15) * 64 + lg * 8;
    #pragma unroll
    for (int tap = 0; tap < 9; ++tap) {
        const __bf16* bsrc = pbase + (tap / 3) * PITCH_ + (tap % 3) * 64;
        const char* wb = (const char*)wlo + tap * 4096;
        #pragma unroll
        for (int ks = 0; ks < 2; ++ks) {
            int cb = ks * 64 + lg * 16;
            bf16x8 a0 = *(const bf16x8*)(wb + SWZ(l15, cb));
            bf16x8 a1 = *(const bf16x8*)(wb + SWZ(16 + l15, cb));
            bf16x8 bv = *(const bf16x8*)(bsrc + ks * 32);
            acc0 = __builtin_amdgcn_mfma_f32_16x16x32_bf16(a0, bv, acc0, 0, 0, 0);
            acc1 = __builtin_amdgcn_mfma_f32_16x16x32_bf16(a1, bv, acc1, 0, 0, 0);
        }
    }
    float* obase = offs + (((size_t)b * 128 + h) * 128 + w0 + px) * 18;
    #pragma unroll
    for (int r = 0; r < 4; ++r) {
        int o = lg * 4 + r;
        if (o < 18) obase[o] = fminf(8.f, fmaxf(-8.f, acc0[r]));
        if (o + 16 < 18) obase[o + 16] = fminf(8.f, fmaxf(-8.f, acc1[r]));
    }
}

// ---------------------------------------------------------------------------
// k_deform: pipelined. Corner gathers 2 taps ahead (2 reg banks), weights
// 2 taps ahead (triple-buffered LDS via linear gl_lds from pre-swizzled wtb),
// samples double-buffered. One barrier per tap.
// ---------------------------------------------------------------------------
struct CBank {
    bf16x8 v00a, v00b, v01a, v01b, v10a, v10b, v11a, v11b;
    float ty, tx;
};

__device__ __forceinline__ void load_corners(int tap, CBank& bk,
                                             const float (*offl)[18], int p,
                                             float fh, float fwp,
                                             const __bf16* xb) {
    float2 od = *(const float2*)&offl[p][2 * tap];
    float sy = od.x + (float)(tap / 3) + fh;     // already includes +16 pad
    float sx = od.y + (float)(tap % 3) + fwp;
    float yf = floorf(sy), xf = floorf(sx);
    bk.ty = sy - yf; bk.tx = sx - xf;
    int yi = (int)yf, xi = (int)xf;
    const __bf16* s0 = xb + (size_t)(yi * HP_ + xi) * 64;
    bk.v00a = ((const bf16x8*)s0)[0];        bk.v00b = ((const bf16x8*)s0)[1];
    bk.v01a = ((const bf16x8*)(s0 + 64))[0]; bk.v01b = ((const bf16x8*)(s0 + 64))[1];
    const __bf16* s1 = s0 + PITCH_;
    bk.v10a = ((const bf16x8*)s1)[0];        bk.v10b = ((const bf16x8*)s1)[1];
    bk.v11a = ((const bf16x8*)(s1 + 64))[0]; bk.v11b = ((const bf16x8*)(s1 + 64))[1];
}

__device__ __forceinline__ void interp_store(const CBank& bk, char* smb,
                                             int p, int cq) {
    float ty = bk.ty, tx = bk.tx;
    float w00 = (1.f - ty) * (1.f - tx), w01 = (1.f - ty) * tx;
    float w10 = ty * (1.f - tx),         w11 = ty * tx;
    bf16x8 h0, h1;
    #pragma unroll
    for (int j = 0; j < 8; ++j) {
        float r0 = w00 * (float)bk.v00a[j] + w01 * (float)bk.v01a[j]
                 + w10 * (float)bk.v10a[j] + w11 * (float)bk.v11a[j];
        float r1 = w00 * (float)bk.v00b[j] + w01 * (float)bk.v01b[j]
                 + w10 * (float)bk.v10b[j] + w11 * (float)bk.v11b[j];
        h0[j] = (__bf16)r0; h1[j] = (__bf16)r1;
    }
    int cb0 = cq * 32;
    *(bf16x8*)(smb + SWZ(p, cb0))      = h0;
    *(bf16x8*)(smb + SWZ(p, cb0 + 16)) = h1;
}

__global__ __launch_bounds__(256) void k_deform(const __bf16* __restrict__ xp,
                                                const float* __restrict__ offs,
                                                const __bf16* __restrict__ wtb,
                                                float* __restrict__ out) {
    __shared__ alignas(16) short wl[3][4096];   // 24 KB, [o][c] swz
    __shared__ alignas(16) short sm[2][4096];   // 16 KB, [px][c] swz
    __shared__ float offl[64][18];              // 4.6 KB

    int gid = blockIdx.x, tid = threadIdx.x;
    int w0 = (gid & 1) * 64, h = (gid >> 1) & 127, b = gid >> 8;
    int lane = tid & 63, wv = tid >> 6, l15 = lane & 15, lg = lane >> 4;
    int p = tid >> 2, cq = tid & 3;
    int m2 = (wv >> 1) * 2, n2 = (wv & 1) * 2;

    const char* wsrc = (const char*)wtb;
    {   // stage wl0 (tap0)
        const char* s = wsrc + wv * 2048 + lane * 16;
        char* d = (char*)wl[0] + wv * 2048;
        gl_lds16(s, d); gl_lds16(s + 1024, d + 1024);
    }
    {   // offl
        const float* osrc = offs + (((size_t)b * 128 + h) * 128 + w0) * 18;
        float* od = &offl[0][0];
        #pragma unroll
        for (int it = 0; it < 5; ++it) {
            int i = tid + it * 256;
            if (i < 1152) od[i] = osrc[i];
        }
    }
    __syncthreads();

    const __bf16* xb = xp + (size_t)b * BPITCH_ + cq * 16;
    float fh  = (float)(h - 1 + 16);
    float fwp = (float)(w0 + p - 1 + 16);

    CBank bk0, bk1;
    load_corners(0, bk0, offl, p, fh, fwp, xb);
    {   // stage wl1 (tap1)
        const char* s = wsrc + 8192 + wv * 2048 + lane * 16;
        char* d = (char*)wl[1] + wv * 2048;
        gl_lds16(s, d); gl_lds16(s + 1024, d + 1024);
    }
    interp_store(bk0, (char*)sm[0], p, cq);
    load_corners(1, bk1, offl, p, fh, fwp, xb);
    __syncthreads();

    f32x4 acc00, acc01, acc10, acc11;
    #pragma unroll
    for (int r = 0; r < 4; ++r) { acc00[r] = 0.f; acc01[r] = 0.f; acc10[r] = 0.f; acc11[r] = 0.f; }

    #pragma unroll
    for (int k = 0; k < 9; ++k) {
        const char* wb = (const char*)wl[k % 3];
        const char* sb = (const char*)sm[k & 1];
        #pragma unroll
        for (int ks = 0; ks < 2; ++ks) {
            int cb = ks * 64 + lg * 16;
            bf16x8 aA = *(const bf16x8*)(wb + SWZ(m2 * 16 + l15, cb));
            bf16x8 aB = *(const bf16x8*)(wb + SWZ((m2 + 1) * 16 + l15, cb));
            bf16x8 bA = *(const bf16x8*)(sb + SWZ(n2 * 16 + l15, cb));
            bf16x8 bB = *(const bf16x8*)(sb + SWZ((n2 + 1) * 16 + l15, cb));
            acc00 = __builtin_amdgcn_mfma_f32_16x16x32_bf16(aA, bA, acc00, 0, 0, 0);
            acc01 = __builtin_amdgcn_mfma_f32_16x16x32_bf16(aA, bB, acc01, 0, 0, 0);
            acc10 = __builtin_amdgcn_mfma_f32_16x16x32_bf16(aB, bA, acc10, 0, 0, 0);
            acc11 = __builtin_amdgcn_mfma_f32_16x16x32_bf16(aB, bB, acc11, 0, 0, 0);
        }
        if (k < 7) {
            // issue next-next corner gathers + weight DMA early (latency hide)
            load_corners(k + 2, (k & 1) ? bk1 : bk0, offl, p, fh, fwp, xb);
            const char* s = wsrc + (k + 2) * 8192 + wv * 2048 + lane * 16;
            char* d = (char*)wl[(k + 2) % 3] + wv * 2048;
            gl_lds16(s, d); gl_lds16(s + 1024, d + 1024);
        }
        if (k < 8) {
            interp_store((k & 1) ? bk0 : bk1, (char*)sm[(k + 1) & 1], p, cq);
            __syncthreads();
        }
    }

    // epilogue: out[b][o][h][w];  D: col = px (l15), row = o (lg*4+r)
    #pragma unroll
    for (int mi = 0; mi < 2; ++mi)
        #pragma unroll
        for (int ni = 0; ni < 2; ++ni) {
            f32x4 a = (mi == 0) ? (ni == 0 ? acc00 : acc01)
                                : (ni == 0 ? acc10 : acc11);
            #pragma unroll
            for (int r = 0; r < 4; ++r) {
                int o  = (m2 + mi) * 16 + lg * 4 + r;
                int px = (n2 + ni) * 16 + l15;
                out[((size_t)b * 64 + o) * 16384 + (size_t)h * 128 + w0 + px] = a[r];
            }
        }
}

// ---------------------------------------------------------------------------
extern "C" void kernel_launch(void* const* d_in, const int* in_sizes, int n_in,
                              void* d_out, int out_size, void* d_ws, size_t ws_size,
                              hipStream_t stream) {
    const float* x      = (const float*)d_in[0];
    const float* weight = (const float*)d_in[1];
    const float* off_w  = (const float*)d_in[2];
    const float* off_b  = (const float*)d_in[3];
    float* out = (float*)d_out;

    char* ws = (char*)d_ws;
    __bf16* xp  = (__bf16*)ws;
    float*  offs = (float*)(ws + XP_BYTES);
    __bf16* wtb = (__bf16*)(ws + XP_BYTES + OFFS_BYTES);
    __bf16* owt = (__bf16*)(ws + XP_BYTES + OFFS_BYTES + WTB_BYTES);

    k_prep<<<4496, 256, 0, stream>>>(x, weight, off_w, xp, wtb, owt);
    k_offconv<<<2048, 256, 0, stream>>>(xp, owt, off_b, offs);
    k_deform<<<2048, 256, 0, stream>>>(xp, offs, wtb, out);
}